// Round 4
// baseline (154.497 us; speedup 1.0000x reference)
//
#include <hip/hip_runtime.h>

#define N_ROWS 4096
#define DIM 1024
#define INV_T (1.0f / 0.07f)
#define BK 32
#define NJT 32   // number of j-tiles (= grid.x of gemm)

typedef __attribute__((ext_vector_type(8))) short short8;
typedef __attribute__((ext_vector_type(4))) float floatx4;

// round-to-nearest-even fp32 -> bf16 (finite inputs only)
__device__ inline unsigned short f2bf(float x) {
    unsigned int u = __float_as_uint(x);
    unsigned int r = (u + 0x7fffu + ((u >> 16) & 1u)) >> 16;
    return (unsigned short)r;
}

// One block per row: computes |z1|, |z2|, <z1,z2>, writes bf16 normalized rows
// and the exact fp32 diagonal logit.
__global__ __launch_bounds__(256) void k_normalize(
    const float* __restrict__ z1, const float* __restrict__ z2,
    unsigned short* __restrict__ z1b, unsigned short* __restrict__ z2b,
    float* __restrict__ diag) {
    const int row = blockIdx.x;
    const int t = threadIdx.x;
    const int lane = t & 63, wave = t >> 6;

    const float4 a = reinterpret_cast<const float4*>(z1 + (size_t)row * DIM)[t];
    const float4 b = reinterpret_cast<const float4*>(z2 + (size_t)row * DIM)[t];

    float s11 = a.x * a.x + a.y * a.y + a.z * a.z + a.w * a.w;
    float s22 = b.x * b.x + b.y * b.y + b.z * b.z + b.w * b.w;
    float s12 = a.x * b.x + a.y * b.y + a.z * b.z + a.w * b.w;

    #pragma unroll
    for (int m = 32; m >= 1; m >>= 1) {
        s11 += __shfl_xor(s11, m, 64);
        s22 += __shfl_xor(s22, m, 64);
        s12 += __shfl_xor(s12, m, 64);
    }

    __shared__ float r11[4], r22[4], r12[4];
    __shared__ float sh_inv1, sh_inv2;
    if (lane == 0) { r11[wave] = s11; r22[wave] = s22; r12[wave] = s12; }
    __syncthreads();
    if (t == 0) {
        float t11 = r11[0] + r11[1] + r11[2] + r11[3];
        float t22 = r22[0] + r22[1] + r22[2] + r22[3];
        float t12 = r12[0] + r12[1] + r12[2] + r12[3];
        float n1 = fmaxf(sqrtf(t11), 1e-12f);
        float n2 = fmaxf(sqrtf(t22), 1e-12f);
        diag[row] = t12 / (n1 * n2) * INV_T;
        sh_inv1 = 1.0f / n1;
        sh_inv2 = 1.0f / n2;
    }
    __syncthreads();
    const float i1 = sh_inv1, i2 = sh_inv2;

    ushort4 pa, pb;
    pa.x = f2bf(a.x * i1); pa.y = f2bf(a.y * i1);
    pa.z = f2bf(a.z * i1); pa.w = f2bf(a.w * i1);
    pb.x = f2bf(b.x * i2); pb.y = f2bf(b.y * i2);
    pb.z = f2bf(b.z * i2); pb.w = f2bf(b.w * i2);
    reinterpret_cast<ushort4*>(z1b)[(size_t)row * (DIM / 4) + t] = pa;
    reinterpret_cast<ushort4*>(z2b)[(size_t)row * (DIM / 4) + t] = pb;
}

// m97-structure MFMA GEMM, fused exp+row-sum epilogue, per-jT partial output.
// Block = 128x128, 4 waves 2x2, each wave 64x64 via 4x4 grid of 16x16x32 MFMA.
// LDS layout XOR-swizzled to kill the 8-way ds_read_b128 bank conflict:
//   LDS[row][c] holds global 16B-chunk (c ^ swz(row)), swz(r)=(r&3)^((r>>2)&3).
// Swizzle applied at staging time by permuting each lane's GLOBAL source
// (global_load_lds forces LDS dest = base + lane*16, so the LDS side is fixed).
// Epilogue: the two wn-waves of each wm cover DIFFERENT columns of the same
// rows — their row-sums are combined through LDS (one store per (jT,i), no
// atomics). R2 bug: plain stores from both wn-waves overwrote each other.
__global__ __launch_bounds__(256) void k_gemm_sumexp(
    const unsigned short* __restrict__ z1b, const unsigned short* __restrict__ z2b,
    float* __restrict__ P) {
    __shared__ unsigned short As[128 * BK];  // 8 KB
    __shared__ unsigned short Bs[128 * BK];  // 8 KB

    const int iT = blockIdx.y, jT = blockIdx.x;
    const int lane = threadIdx.x & 63, wave = threadIdx.x >> 6;
    const int wm = wave >> 1, wn = wave & 1;     // 2x2 wave grid
    const int ml = lane & 15, q = lane >> 4;     // MFMA lane decomposition
    const int i0 = iT * 128, j0 = jT * 128;

    // staging: chunk = 16 rows x 32 elems = 1 KB = one wave-issue.
    // lane l: row = l>>2, global 16B-chunk = (l&3) ^ swz(row).
    const int sr = lane >> 2;
    const int scw = (lane & 3) ^ ((sr & 3) ^ ((sr >> 2) & 3));  // swizzled chunk
    const int sc = scw * 8;                                      // element offset

    // fragment-read swizzle (tile bases are multiples of 16 so swz(row)=swz(ml))
    const int rswz = (ml & 3) ^ ((ml >> 2) & 3);

    floatx4 acc[4][4];
    #pragma unroll
    for (int mt = 0; mt < 4; ++mt)
        #pragma unroll
        for (int nt = 0; nt < 4; ++nt)
            acc[mt][nt] = (floatx4){0.f, 0.f, 0.f, 0.f};

    for (int k0 = 0; k0 < DIM; k0 += BK) {
        #pragma unroll
        for (int c = 0; c < 2; ++c) {
            const int chunk = wave * 2 + c;          // 0..7
            const int row = chunk * 16 + sr;         // 0..127
            const unsigned short* gA = z1b + (size_t)(i0 + row) * DIM + k0 + sc;
            const unsigned short* gB = z2b + (size_t)(j0 + row) * DIM + k0 + sc;
            __builtin_amdgcn_global_load_lds(
                (const __attribute__((address_space(1))) void*)gA,
                (__attribute__((address_space(3))) void*)(As + chunk * 512), 16, 0, 0);
            __builtin_amdgcn_global_load_lds(
                (const __attribute__((address_space(1))) void*)gB,
                (__attribute__((address_space(3))) void*)(Bs + chunk * 512), 16, 0, 0);
        }
        __syncthreads();

        short8 af[4], bf[4];
        #pragma unroll
        for (int t = 0; t < 4; ++t) {
            af[t] = *reinterpret_cast<const short8*>(
                As + (wm * 64 + t * 16 + ml) * BK + ((q ^ rswz) * 8));
            bf[t] = *reinterpret_cast<const short8*>(
                Bs + (wn * 64 + t * 16 + ml) * BK + ((q ^ rswz) * 8));
        }
        #pragma unroll
        for (int mt = 0; mt < 4; ++mt)
            #pragma unroll
            for (int nt = 0; nt < 4; ++nt)
                acc[mt][nt] = __builtin_amdgcn_mfma_f32_16x16x32_bf16(
                    af[mt], bf[nt], acc[mt][nt], 0, 0, 0);
        __syncthreads();
    }

    // Epilogue. C/D layout: col=lane&15, row=q*4+reg. exp + sum over this
    // wave's 64 columns, butterfly across the 16 ml-lanes; then combine the
    // two wn-waves through LDS and store one partial per (jT, i).
    float vv[4][4];
    #pragma unroll
    for (int mt = 0; mt < 4; ++mt) {
        #pragma unroll
        for (int r = 0; r < 4; ++r) {
            float v = 0.f;
            #pragma unroll
            for (int nt = 0; nt < 4; ++nt)
                v += __expf(acc[mt][nt][r] * INV_T);
            v += __shfl_xor(v, 1, 64);
            v += __shfl_xor(v, 2, 64);
            v += __shfl_xor(v, 4, 64);
            v += __shfl_xor(v, 8, 64);
            vv[mt][r] = v;
        }
    }
    float* Pl = reinterpret_cast<float*>(As);  // reuse (all LDS reads done)
    if (wn == 1 && ml == 0) {
        #pragma unroll
        for (int mt = 0; mt < 4; ++mt)
            #pragma unroll
            for (int r = 0; r < 4; ++r)
                Pl[wm * 64 + mt * 16 + q * 4 + r] = vv[mt][r];
    }
    __syncthreads();
    if (wn == 0 && ml == 0) {
        #pragma unroll
        for (int mt = 0; mt < 4; ++mt)
            #pragma unroll
            for (int r = 0; r < 4; ++r) {
                const int ri = wm * 64 + mt * 16 + q * 4 + r;
                P[(size_t)jT * N_ROWS + i0 + ri] = vv[mt][r] + Pl[ri];
            }
    }
}

// Single block, 1024 threads: S_i = sum_jT P[jT][i]; loss = mean(log S_i - diag_i).
__global__ __launch_bounds__(1024) void k_finalize(
    const float* __restrict__ P, const float* __restrict__ diag,
    float* __restrict__ out) {
    const int t = threadIdx.x;
    float acc = 0.f;
    #pragma unroll
    for (int rep = 0; rep < N_ROWS / 1024; ++rep) {
        const int i = rep * 1024 + t;
        float s = 0.f;
        #pragma unroll
        for (int jt = 0; jt < NJT; ++jt)
            s += P[(size_t)jt * N_ROWS + i];
        acc += logf(s) - diag[i];
    }
    #pragma unroll
    for (int m = 32; m >= 1; m >>= 1)
        acc += __shfl_xor(acc, m, 64);
    __shared__ float r[16];
    if ((t & 63) == 0) r[t >> 6] = acc;
    __syncthreads();
    if (t == 0) {
        float tot = 0.f;
        #pragma unroll
        for (int w = 0; w < 16; ++w) tot += r[w];
        out[0] = tot / (float)N_ROWS;
    }
}

extern "C" void kernel_launch(void* const* d_in, const int* in_sizes, int n_in,
                              void* d_out, int out_size, void* d_ws, size_t ws_size,
                              hipStream_t stream) {
    const float* z1 = (const float*)d_in[0];
    const float* z2 = (const float*)d_in[1];

    char* ws = (char*)d_ws;
    unsigned short* z1b = (unsigned short*)ws;                                   // 8 MB
    unsigned short* z2b = (unsigned short*)(ws + (size_t)N_ROWS * DIM * 2);      // 8 MB
    float* diag = (float*)(ws + (size_t)N_ROWS * DIM * 4);                       // 16 KB
    float* P = diag + N_ROWS;                                                    // 512 KB

    k_normalize<<<N_ROWS, 256, 0, stream>>>(z1, z2, z1b, z2b, diag);
    k_gemm_sumexp<<<dim3(NJT, 32), 256, 0, stream>>>(z1b, z2b, P);
    k_finalize<<<1, 1024, 0, stream>>>(P, diag, (float*)d_out);
}

// Round 5
// 129.045 us; speedup vs baseline: 1.1972x; 1.1972x over previous
//
#include <hip/hip_runtime.h>

#define N_ROWS 4096
#define DIM 1024
#define INV_T (1.0f / 0.07f)
#define EXP_SCALE (INV_T * 1.44269504088896f)  // x/T in log2 units for v_exp_f32
#define BK 32
#define NJT 32   // number of j-tiles (= grid.x of gemm)

typedef __attribute__((ext_vector_type(8))) short short8;
typedef __attribute__((ext_vector_type(4))) float floatx4;

// round-to-nearest-even fp32 -> bf16 (finite inputs only)
__device__ inline unsigned short f2bf(float x) {
    unsigned int u = __float_as_uint(x);
    unsigned int r = (u + 0x7fffu + ((u >> 16) & 1u)) >> 16;
    return (unsigned short)r;
}

// One WAVE per row (4 rows / 256-thread block): no barriers, no LDS, no
// serialized thread-0 section. Lane holds 16 elems of each input; 6-round
// butterfly gives every lane the norms; sqrt/rcp computed redundantly.
__global__ __launch_bounds__(256) void k_normalize(
    const float* __restrict__ z1, const float* __restrict__ z2,
    unsigned short* __restrict__ z1b, unsigned short* __restrict__ z2b,
    float* __restrict__ diag) {
    const int lane = threadIdx.x & 63, wave = threadIdx.x >> 6;
    const int row = blockIdx.x * 4 + wave;

    const float4* A = reinterpret_cast<const float4*>(z1 + (size_t)row * DIM);
    const float4* B = reinterpret_cast<const float4*>(z2 + (size_t)row * DIM);
    float4 a[4], b[4];
    #pragma unroll
    for (int rep = 0; rep < 4; ++rep) {
        a[rep] = A[lane + 64 * rep];
        b[rep] = B[lane + 64 * rep];
    }

    float s11 = 0.f, s22 = 0.f, s12 = 0.f;
    #pragma unroll
    for (int rep = 0; rep < 4; ++rep) {
        s11 += a[rep].x * a[rep].x + a[rep].y * a[rep].y
             + a[rep].z * a[rep].z + a[rep].w * a[rep].w;
        s22 += b[rep].x * b[rep].x + b[rep].y * b[rep].y
             + b[rep].z * b[rep].z + b[rep].w * b[rep].w;
        s12 += a[rep].x * b[rep].x + a[rep].y * b[rep].y
             + a[rep].z * b[rep].z + a[rep].w * b[rep].w;
    }
    #pragma unroll
    for (int m = 32; m >= 1; m >>= 1) {
        s11 += __shfl_xor(s11, m, 64);
        s22 += __shfl_xor(s22, m, 64);
        s12 += __shfl_xor(s12, m, 64);
    }

    const float n1 = fmaxf(sqrtf(s11), 1e-12f);
    const float n2 = fmaxf(sqrtf(s22), 1e-12f);
    if (lane == 0) diag[row] = s12 / (n1 * n2) * INV_T;
    const float i1 = 1.0f / n1, i2 = 1.0f / n2;

    ushort4* O1 = reinterpret_cast<ushort4*>(z1b) + (size_t)row * (DIM / 4);
    ushort4* O2 = reinterpret_cast<ushort4*>(z2b) + (size_t)row * (DIM / 4);
    #pragma unroll
    for (int rep = 0; rep < 4; ++rep) {
        ushort4 pa, pb;
        pa.x = f2bf(a[rep].x * i1); pa.y = f2bf(a[rep].y * i1);
        pa.z = f2bf(a[rep].z * i1); pa.w = f2bf(a[rep].w * i1);
        pb.x = f2bf(b[rep].x * i2); pb.y = f2bf(b[rep].y * i2);
        pb.z = f2bf(b[rep].z * i2); pb.w = f2bf(b[rep].w * i2);
        O1[lane + 64 * rep] = pa;
        O2[lane + 64 * rep] = pb;
    }
}

// m97-structure MFMA GEMM, fused exp+row-sum epilogue, per-jT partial output.
// Block = 128x128, 4 waves 2x2, each wave 64x64 via 4x4 grid of 16x16x32 MFMA.
// LDS layout XOR-swizzled (measured neutral on SQ_LDS_BANK_CONFLICT — the
// 4 cyc/ds_read_b128 residual is structural b128 phasing; swizzle kept, free).
// Epilogue: two wn-waves cover different columns of the same rows; combined
// through LDS, one store per (jT, i), no atomics.
__global__ __launch_bounds__(256) void k_gemm_sumexp(
    const unsigned short* __restrict__ z1b, const unsigned short* __restrict__ z2b,
    float* __restrict__ P) {
    __shared__ unsigned short As[128 * BK];  // 8 KB
    __shared__ unsigned short Bs[128 * BK];  // 8 KB

    const int iT = blockIdx.y, jT = blockIdx.x;
    const int lane = threadIdx.x & 63, wave = threadIdx.x >> 6;
    const int wm = wave >> 1, wn = wave & 1;     // 2x2 wave grid
    const int ml = lane & 15, q = lane >> 4;     // MFMA lane decomposition
    const int i0 = iT * 128, j0 = jT * 128;

    // staging: chunk = 16 rows x 32 elems = 1 KB = one wave-issue.
    const int sr = lane >> 2;
    const int scw = (lane & 3) ^ ((sr & 3) ^ ((sr >> 2) & 3));  // swizzled chunk
    const int sc = scw * 8;
    const int rswz = (ml & 3) ^ ((ml >> 2) & 3);

    floatx4 acc[4][4];
    #pragma unroll
    for (int mt = 0; mt < 4; ++mt)
        #pragma unroll
        for (int nt = 0; nt < 4; ++nt)
            acc[mt][nt] = (floatx4){0.f, 0.f, 0.f, 0.f};

    for (int k0 = 0; k0 < DIM; k0 += BK) {
        #pragma unroll
        for (int c = 0; c < 2; ++c) {
            const int chunk = wave * 2 + c;          // 0..7
            const int row = chunk * 16 + sr;         // 0..127
            const unsigned short* gA = z1b + (size_t)(i0 + row) * DIM + k0 + sc;
            const unsigned short* gB = z2b + (size_t)(j0 + row) * DIM + k0 + sc;
            __builtin_amdgcn_global_load_lds(
                (const __attribute__((address_space(1))) void*)gA,
                (__attribute__((address_space(3))) void*)(As + chunk * 512), 16, 0, 0);
            __builtin_amdgcn_global_load_lds(
                (const __attribute__((address_space(1))) void*)gB,
                (__attribute__((address_space(3))) void*)(Bs + chunk * 512), 16, 0, 0);
        }
        __syncthreads();

        short8 af[4], bf[4];
        #pragma unroll
        for (int t = 0; t < 4; ++t) {
            af[t] = *reinterpret_cast<const short8*>(
                As + (wm * 64 + t * 16 + ml) * BK + ((q ^ rswz) * 8));
            bf[t] = *reinterpret_cast<const short8*>(
                Bs + (wn * 64 + t * 16 + ml) * BK + ((q ^ rswz) * 8));
        }
        #pragma unroll
        for (int mt = 0; mt < 4; ++mt)
            #pragma unroll
            for (int nt = 0; nt < 4; ++nt)
                acc[mt][nt] = __builtin_amdgcn_mfma_f32_16x16x32_bf16(
                    af[mt], bf[nt], acc[mt][nt], 0, 0, 0);
        __syncthreads();
    }

    // Epilogue. C/D layout: col=lane&15, row=q*4+reg.
    float vv[4][4];
    #pragma unroll
    for (int mt = 0; mt < 4; ++mt) {
        #pragma unroll
        for (int r = 0; r < 4; ++r) {
            float v = 0.f;
            #pragma unroll
            for (int nt = 0; nt < 4; ++nt)
                v += __builtin_amdgcn_exp2f(acc[mt][nt][r] * EXP_SCALE);
            v += __shfl_xor(v, 1, 64);
            v += __shfl_xor(v, 2, 64);
            v += __shfl_xor(v, 4, 64);
            v += __shfl_xor(v, 8, 64);
            vv[mt][r] = v;
        }
    }
    float* Pl = reinterpret_cast<float*>(As);  // reuse (all LDS reads done)
    if (wn == 1 && ml == 0) {
        #pragma unroll
        for (int mt = 0; mt < 4; ++mt)
            #pragma unroll
            for (int r = 0; r < 4; ++r)
                Pl[wm * 64 + mt * 16 + q * 4 + r] = vv[mt][r];
    }
    __syncthreads();
    if (wn == 0 && ml == 0) {
        #pragma unroll
        for (int mt = 0; mt < 4; ++mt)
            #pragma unroll
            for (int r = 0; r < 4; ++r) {
                const int ri = wm * 64 + mt * 16 + q * 4 + r;
                P[jT * N_ROWS + i0 + ri] = vv[mt][r] + Pl[ri];
            }
    }
}

// 32 blocks x 128 threads: one row per thread, coalesced P reads,
// block partial-sum -> atomicAdd into pre-zeroed out[0].
__global__ __launch_bounds__(128) void k_finalize(
    const float* __restrict__ P, const float* __restrict__ diag,
    float* __restrict__ out) {
    const int t = threadIdx.x;
    const int i = blockIdx.x * 128 + t;
    float s = 0.f;
    #pragma unroll
    for (int jt = 0; jt < NJT; ++jt)
        s += P[jt * N_ROWS + i];
    float v = logf(s) - diag[i];
    #pragma unroll
    for (int m = 32; m >= 1; m >>= 1)
        v += __shfl_xor(v, m, 64);
    __shared__ float r[2];
    if ((t & 63) == 0) r[t >> 6] = v;
    __syncthreads();
    if (t == 0) atomicAdd(out, (r[0] + r[1]) * (1.0f / N_ROWS));
}

extern "C" void kernel_launch(void* const* d_in, const int* in_sizes, int n_in,
                              void* d_out, int out_size, void* d_ws, size_t ws_size,
                              hipStream_t stream) {
    const float* z1 = (const float*)d_in[0];
    const float* z2 = (const float*)d_in[1];

    char* ws = (char*)d_ws;
    unsigned short* z1b = (unsigned short*)ws;                                   // 8 MB
    unsigned short* z2b = (unsigned short*)(ws + (size_t)N_ROWS * DIM * 2);      // 8 MB
    float* diag = (float*)(ws + (size_t)N_ROWS * DIM * 4);                       // 16 KB
    float* P = diag + N_ROWS;                                                    // 512 KB

    hipMemsetAsync(d_out, 0, sizeof(float), stream);
    k_normalize<<<N_ROWS / 4, 256, 0, stream>>>(z1, z2, z1b, z2b, diag);
    k_gemm_sumexp<<<dim3(NJT, 32), 256, 0, stream>>>(z1b, z2b, P);
    k_finalize<<<32, 128, 0, stream>>>(P, diag, (float*)d_out);
}